// Round 5
// baseline (343.351 us; speedup 1.0000x reference)
//
#include <hip/hip_runtime.h>
#include <hip/hip_bf16.h>
#include <stdint.h>

// Problem constants
#define B_ 16
#define L_ 4096
#define D_ 256
#define M_ (B_*L_)   // 65536 tokens
#define N_ 768       // [loop | parent | child] concatenated output cols

typedef __attribute__((ext_vector_type(8))) short bf16x8;
typedef __attribute__((ext_vector_type(4))) float f32x4;
typedef __attribute__((ext_vector_type(4))) int i32x4;

__device__ __forceinline__ float bf2f(unsigned short u) {
  union { unsigned int i; float f; } v; v.i = ((unsigned int)u) << 16; return v.f;
}
__device__ __forceinline__ unsigned short f2bf(float f) {
  __hip_bfloat16 h = __float2bfloat16(f);
  return *reinterpret_cast<unsigned short*>(&h);
}
__device__ __forceinline__ void async16(const void* g, void* l) {
  __builtin_amdgcn_global_load_lds((const __attribute__((address_space(1))) void*)g,
                                   (__attribute__((address_space(3))) void*)l, 16, 0, 0);
}
__device__ __forceinline__ float sigmoidf_(float z) {
  return 1.f / (1.f + __expf(-z));
}

// ---------------------------------------------------------------------------
// Kernel PRE (fused): blocks 0..2047   : gate logits + x->bf16
//                     blocks 2048..2815: weight transpose -> WbT bf16
//                     blocks 2816..2831: per-batch CSR (hist+scan+fill)
//                     block  2832      : zero row0 done-counter
// ---------------------------------------------------------------------------
__global__ __launch_bounds__(256) void k_pre(
    const float* __restrict__ x, const int* __restrict__ deps,
    const int* __restrict__ parent, const int* __restrict__ mask,
    const float* __restrict__ wlg, const float* __restrict__ blg,
    const float* __restrict__ wcg, const float* __restrict__ bcg,
    const float* __restrict__ wpg, const float* __restrict__ bpg,
    const float* __restrict__ Epg, const float* __restrict__ Ecg,
    const float* __restrict__ Wl, const float* __restrict__ Wp,
    const float* __restrict__ Wc,
    unsigned short* __restrict__ xb, float4* __restrict__ gates,
    unsigned short* __restrict__ WbT,
    int* __restrict__ cnt, int* __restrict__ off, int* __restrict__ lists,
    int* __restrict__ counter)
{
  __shared__ int hist[4096];
  __shared__ int tot[256];
  const int bx = blockIdx.x;
  const int tid = threadIdx.x;

  if (bx >= 2048) {
    if (bx < 2816) {                 // ---- weight transpose ----
      const int n = bx - 2048;
      const float* W = (n < 256) ? Wl : ((n < 512) ? Wp : Wc);
      WbT[(size_t)n * 256 + tid] = f2bf(W[(size_t)tid * 256 + (n & 255)]);
    } else if (bx < 2832) {          // ---- per-batch CSR ----
      const int b = bx - 2816;
      const int base = b << 12;
      #pragma unroll
      for (int j = 0; j < 16; ++j) hist[tid + j * 256] = 0;
      __syncthreads();
      for (int j = 0; j < 16; ++j) {
        const int i = base + j * 256 + tid;
        if (mask[i]) {
          const int p = parent[i];
          if (p > 0 && mask[base + p]) atomicAdd(&hist[p], 1);
        }
      }
      __syncthreads();
      int v[16], s = 0;
      #pragma unroll
      for (int j = 0; j < 16; ++j) { v[j] = hist[tid * 16 + j]; s += v[j]; }
      tot[tid] = s;
      __syncthreads();
      for (int o = 1; o < 256; o <<= 1) {
        int xx = (tid >= o) ? tot[tid - o] : 0;
        __syncthreads();
        tot[tid] += xx;
        __syncthreads();
      }
      int run = tot[tid] - s;        // exclusive prefix
      #pragma unroll
      for (int j = 0; j < 16; ++j) {
        const int k = tid * 16 + j;
        cnt[base + k] = v[j];
        off[base + k] = run;
        hist[k] = run;               // becomes the fill cursor
        run += v[j];
      }
      __syncthreads();
      for (int j = 0; j < 16; ++j) {
        const int i = base + j * 256 + tid;
        if (mask[i]) {
          const int p = parent[i];
          if (p > 0 && mask[base + p]) {
            const int pos = atomicAdd(&hist[p], 1);
            lists[base + pos] = i;
          }
        }
      }
    } else {                         // ---- zero counter ----
      if (tid == 0) *counter = 0;
    }
    return;
  }

  // ---- gates + bf16 convert ----
  const int lane = tid & 63;
  const int gw = (bx * 256 + tid) >> 6;
  const float4 wl4 = ((const float4*)wlg)[lane];
  const float4 wc4 = ((const float4*)wcg)[lane];
  const float4 wp4 = ((const float4*)wpg)[lane];
  const float bl0 = blg[0], bc0 = bcg[0], bp0 = bpg[0];
  for (int t = 0; t < 8; ++t) {
    const int i = gw * 8 + t;
    float4 xv = ((const float4*)x)[(size_t)i * 64 + lane];
    float sl = xv.x * wl4.x + xv.y * wl4.y + xv.z * wl4.z + xv.w * wl4.w;
    float sc = xv.x * wc4.x + xv.y * wc4.y + xv.z * wc4.z + xv.w * wc4.w;
    float sp = xv.x * wp4.x + xv.y * wp4.y + xv.z * wp4.z + xv.w * wp4.w;
    #pragma unroll
    for (int o = 32; o; o >>= 1) {
      sl += __shfl_xor(sl, o);
      sc += __shfl_xor(sc, o);
      sp += __shfl_xor(sp, o);
    }
    ushort4 u;
    u.x = f2bf(xv.x); u.y = f2bf(xv.y); u.z = f2bf(xv.z); u.w = f2bf(xv.w);
    ((ushort4*)xb)[(size_t)i * 64 + lane] = u;
    if (lane == 0) {
      int d = deps[i];
      float gl = sigmoidf_(sl + bl0);
      float gp = sigmoidf_(sp + bp0 + Epg[d]);
      float gc = sigmoidf_(sc + bc0 + Ecg[d]);
      gates[i] = make_float4(gl, gp, gc, 0.f);
    }
  }
}

// ---------------------------------------------------------------------------
// Kernel B: Y[65536][768] (bf16) = xb @ Wb.  128x128 tile, 4 waves, BK=64.
// 1-D grid, mb=bid/6 nb=bid%6 so the 6 blocks sharing an A-tile run
// back-to-back -> A fetched from HBM once, L3-hits for the rest.
// ---------------------------------------------------------------------------
__global__ __launch_bounds__(256) void k_gemm(
    const unsigned short* __restrict__ A,    // [M][256] bf16
    const unsigned short* __restrict__ Bt,   // [768][256] bf16 (N-major)
    unsigned short* __restrict__ Y)          // [M][768] bf16
{
  __shared__ unsigned short sh[2 * 128 * 64];
  unsigned short* lA = sh;
  unsigned short* lB = sh + 128 * 64;
  const int tid = threadIdx.x;
  const int wid = tid >> 6, lane = tid & 63;
  const int wm = wid >> 1, wn = wid & 1;
  const int bid = blockIdx.x;
  const int mb = bid / 6, nb = bid % 6;

  f32x4 acc[4][4] = {};
  const unsigned short* Ag = A + (size_t)mb * 128 * 256;
  const unsigned short* Bg = Bt + (size_t)nb * 128 * 256;
  const int srow = wid * 8 + (lane >> 3);   // staging row within 32-row sweep
  const int scol = (lane & 7) * 8;          // staging col (bf16)

  for (int kb = 0; kb < 256; kb += 64) {
    #pragma unroll
    for (int s = 0; s < 4; ++s) {
      char* dA = (char*)lA + s * 4096 + wid * 1024 + lane * 16;
      char* dB = (char*)lB + s * 4096 + wid * 1024 + lane * 16;
      async16(Ag + (size_t)(s * 32 + srow) * 256 + kb + scol, dA);
      async16(Bg + (size_t)(s * 32 + srow) * 256 + kb + scol, dB);
    }
    __syncthreads();
    #pragma unroll
    for (int kk = 0; kk < 64; kk += 32) {
      const int ko = kk + (lane >> 4) * 8;
      bf16x8 af[4], bv[4];
      #pragma unroll
      for (int m = 0; m < 4; ++m)
        af[m] = *(const bf16x8*)&lA[(wm * 64 + m * 16 + (lane & 15)) * 64 + ko];
      #pragma unroll
      for (int n = 0; n < 4; ++n)
        bv[n] = *(const bf16x8*)&lB[(wn * 64 + n * 16 + (lane & 15)) * 64 + ko];
      #pragma unroll
      for (int m = 0; m < 4; ++m)
        #pragma unroll
        for (int n = 0; n < 4; ++n)
          acc[m][n] = __builtin_amdgcn_mfma_f32_16x16x32_bf16(af[m], bv[n], acc[m][n], 0, 0, 0);
    }
    __syncthreads();
  }

  // Epilogue: fragments -> LDS (bf16, [128][128]) -> coalesced 16B stores.
  #pragma unroll
  for (int m = 0; m < 4; ++m)
    #pragma unroll
    for (int n = 0; n < 4; ++n)
      #pragma unroll
      for (int r = 0; r < 4; ++r)
        sh[(wm * 64 + m * 16 + (lane >> 4) * 4 + r) * 128 + wn * 64 + n * 16 + (lane & 15)]
            = f2bf(acc[m][n][r]);
  __syncthreads();
  #pragma unroll
  for (int s = 0; s < 8; ++s) {
    const int o = s * 4096 + tid * 16;          // byte offset in 32KB tile
    const int row = o >> 8;                     // 256 B per row (128 bf16)
    const int colu = (o & 255) >> 1;            // bf16 col
    *(i32x4*)&Y[(size_t)(mb * 128 + row) * 768 + nb * 128 + colu] =
        *(const i32x4*)((const char*)sh + o);
  }
}

// ---------------------------------------------------------------------------
// Kernel F: fused combine + child gather. One wave per output row; writes
// each row exactly once (zeros if masked). No atomics.
// ---------------------------------------------------------------------------
__global__ __launch_bounds__(256) void k_fused(
    const unsigned short* __restrict__ Y, const float4* __restrict__ gates,
    const int* __restrict__ parent, const int* __restrict__ deps,
    const int* __restrict__ mask, const int* __restrict__ cnt,
    const int* __restrict__ off, const int* __restrict__ lists,
    const float* __restrict__ b_loop, const float* __restrict__ b_parent,
    const float* __restrict__ b_child,
    const float* __restrict__ Epw, const float* __restrict__ Ecw,
    float* __restrict__ out)
{
  const int lane = threadIdx.x & 63;
  const int i = blockIdx.x * 4 + (threadIdx.x >> 6);   // output row (token)
  const int b = i >> 12;
  float4* orow = (float4*)(out + (size_t)i * 256) + lane;
  if (!mask[i]) { *orow = make_float4(0.f, 0.f, 0.f, 0.f); return; }

  const float4 g = gates[i];
  const int p = parent[i], d = deps[i];
  const float4 bl = ((const float4*)b_loop)[lane];
  const float4 bp = ((const float4*)b_parent)[lane];
  const ushort4 yl = ((const ushort4*)(Y + (size_t)i * 768))[lane];
  const ushort4 z  = ((const ushort4*)(Y + (size_t)((b << 12) + p) * 768 + 256))[lane];
  const float4 e   = ((const float4*)Epw)[d * 64 + lane];
  float4 o;
  o.x = g.x * (bf2f(yl.x) + bl.x) + g.y * (bf2f(z.x) + bp.x + e.x);
  o.y = g.x * (bf2f(yl.y) + bl.y) + g.y * (bf2f(z.y) + bp.y + e.y);
  o.z = g.x * (bf2f(yl.z) + bl.z) + g.y * (bf2f(z.z) + bp.z + e.z);
  o.w = g.x * (bf2f(yl.w) + bl.w) + g.y * (bf2f(z.w) + bp.w + e.w);

  const int n = cnt[i];
  if (n) {
    const int o0 = off[i];
    const float4 bc = ((const float4*)b_child)[lane];
    for (int k = 0; k < n; ++k) {
      const int c = lists[(b << 12) + o0 + k];
      const float gc = ((const float*)gates)[c * 4 + 2];
      const int dc = deps[c];
      const ushort4 yc = ((const ushort4*)(Y + (size_t)c * 768 + 512))[lane];
      const float4 ec = ((const float4*)Ecw)[dc * 64 + lane];
      o.x += gc * (bf2f(yc.x) + bc.x + ec.x);
      o.y += gc * (bf2f(yc.y) + bc.y + ec.y);
      o.z += gc * (bf2f(yc.z) + bc.z + ec.z);
      o.w += gc * (bf2f(yc.w) + bc.w + ec.w);
    }
  }
  *orow = o;
}

// ---------------------------------------------------------------------------
// Kernel R0: row-0 child reduction, single dispatch (last-block-done).
// 1024 blocks: each reduces 64 tokens' dest==0 contributions to a partial;
// the last block to finish sums all partials and adds into out rows 0.
// Runs AFTER k_fused (adds on top of the loop+parent value it wrote).
// ---------------------------------------------------------------------------
__global__ __launch_bounds__(256) void k_row0(
    const unsigned short* __restrict__ Y, const float4* __restrict__ gates,
    const int* __restrict__ parent, const int* __restrict__ deps,
    const int* __restrict__ mask, const float* __restrict__ b_child,
    const float* __restrict__ Ecw, float4* __restrict__ partial,
    int* __restrict__ counter, float* __restrict__ out)
{
  const int blk = blockIdx.x;          // 0..1023
  const int b = blk >> 6;
  const int lane = threadIdx.x & 63;
  const int wid = threadIdx.x >> 6;
  float4 acc = make_float4(0.f, 0.f, 0.f, 0.f);
  if (mask[b << 12]) {
    const float4 bc = ((const float4*)b_child)[lane];
    const int tbase = (b << 12) + (blk & 63) * 64 + wid * 16;
    for (int t = 0; t < 16; ++t) {
      const int i = tbase + t;
      const int mi = mask[i];
      const int p = parent[i];
      if (mi && p != 0) continue;      // keep only dest==0 contributions
      const float gc = ((const float*)gates)[i * 4 + 2];
      const int d = deps[i];
      const ushort4 yc = ((const ushort4*)(Y + (size_t)i * 768 + 512))[lane];
      const float4 ec = ((const float4*)Ecw)[d * 64 + lane];
      acc.x += gc * (bf2f(yc.x) + bc.x + ec.x);
      acc.y += gc * (bf2f(yc.y) + bc.y + ec.y);
      acc.z += gc * (bf2f(yc.z) + bc.z + ec.z);
      acc.w += gc * (bf2f(yc.w) + bc.w + ec.w);
    }
  }
  __shared__ float4 red[4][64];
  __shared__ int lastflag;
  red[wid][lane] = acc;
  __syncthreads();
  if (wid == 0) {
    float4 a0 = red[0][lane], a1 = red[1][lane], a2 = red[2][lane], a3 = red[3][lane];
    a0.x += a1.x + a2.x + a3.x;
    a0.y += a1.y + a2.y + a3.y;
    a0.z += a1.z + a2.z + a3.z;
    a0.w += a1.w + a2.w + a3.w;
    partial[blk * 64 + lane] = a0;
  }
  __threadfence();                     // release partial stores (device scope)
  __syncthreads();
  if (threadIdx.x == 0)
    lastflag = (atomicAdd(counter, 1) == 1023);
  __syncthreads();
  if (!lastflag) return;
  __threadfence();                     // acquire: all partials visible
  for (int w = threadIdx.x; w < 1024; w += 256) {
    const int bb = w >> 6, c = w & 63;
    if (!mask[bb << 12]) continue;
    float4 s = make_float4(0.f, 0.f, 0.f, 0.f);
    for (int k = 0; k < 64; ++k) {
      const float4 v = partial[(bb * 64 + k) * 64 + c];
      s.x += v.x; s.y += v.y; s.z += v.z; s.w += v.w;
    }
    float4* orow = (float4*)(out + (size_t)(bb << 12) * 256) + c;
    float4 o = *orow;
    o.x += s.x; o.y += s.y; o.z += s.z; o.w += s.w;
    *orow = o;
  }
}

// ---------------------------------------------------------------------------
extern "C" void kernel_launch(void* const* d_in, const int* in_sizes, int n_in,
                              void* d_out, int out_size, void* d_ws, size_t ws_size,
                              hipStream_t stream) {
  const float* x        = (const float*)d_in[0];
  const int*   parent   = (const int*)d_in[1];
  const int*   deps     = (const int*)d_in[2];
  const int*   mask     = (const int*)d_in[3];
  const float* W_loop   = (const float*)d_in[4];
  const float* b_loop   = (const float*)d_in[5];
  const float* W_child  = (const float*)d_in[6];
  const float* b_child  = (const float*)d_in[7];
  const float* W_parent = (const float*)d_in[8];
  const float* b_parent = (const float*)d_in[9];
  const float* wlg      = (const float*)d_in[10];
  const float* blg      = (const float*)d_in[11];
  const float* wcg      = (const float*)d_in[12];
  const float* bcg      = (const float*)d_in[13];
  const float* wpg      = (const float*)d_in[14];
  const float* bpg      = (const float*)d_in[15];
  const float* Epw      = (const float*)d_in[16];
  const float* Ecw      = (const float*)d_in[17];
  const float* Epg      = (const float*)d_in[18];
  const float* Ecg      = (const float*)d_in[19];
  float* out = (float*)d_out;

  // Workspace layout (~136.5 MB). partial aliases xb (xb dead after gemm).
  char* ws = (char*)d_ws;
  unsigned short* xb  = (unsigned short*)ws;                         // 32 MB
  float4* partial     = (float4*)ws;                                 // 1 MB (alias, post-gemm)
  unsigned short* WbT = (unsigned short*)(ws + 33554432);            // 384 KB
  float4* gates       = (float4*)(ws + 33947648);                    // 1 MB
  unsigned short* Yv  = (unsigned short*)(ws + 34996224);            // 96 MB
  int* cnt            = (int*)(ws + 135659520);                      // 256 KB
  int* off            = (int*)(ws + 135921664);                      // 256 KB
  int* lists          = (int*)(ws + 136183808);                      // 256 KB
  int* counter        = (int*)(ws + 136445952);                      // 4 B

  k_pre<<<2833, 256, 0, stream>>>(x, deps, parent, mask, wlg, blg, wcg, bcg,
                                  wpg, bpg, Epg, Ecg, W_loop, W_parent, W_child,
                                  xb, gates, WbT, cnt, off, lists, counter);
  k_gemm<<<3072, 256, 0, stream>>>(xb, WbT, Yv);
  k_fused<<<16384, 256, 0, stream>>>(Yv, gates, parent, deps, mask, cnt, off,
                                     lists, b_loop, b_parent, b_child,
                                     Epw, Ecw, out);
  k_row0<<<1024, 256, 0, stream>>>(Yv, gates, parent, deps, mask, b_child,
                                   Ecw, partial, counter, out);
}

// Round 6
// 278.833 us; speedup vs baseline: 1.2314x; 1.2314x over previous
//
#include <hip/hip_runtime.h>
#include <hip/hip_bf16.h>
#include <stdint.h>

// Problem constants
#define B_ 16
#define L_ 4096
#define D_ 256
#define M_ (B_*L_)   // 65536 tokens
#define N_ 768       // [loop | parent | child] concatenated output cols

typedef __attribute__((ext_vector_type(8))) short bf16x8;
typedef __attribute__((ext_vector_type(4))) float f32x4;
typedef __attribute__((ext_vector_type(4))) int i32x4;

__device__ __forceinline__ float bf2f(unsigned short u) {
  union { unsigned int i; float f; } v; v.i = ((unsigned int)u) << 16; return v.f;
}
__device__ __forceinline__ unsigned short f2bf(float f) {
  __hip_bfloat16 h = __float2bfloat16(f);
  return *reinterpret_cast<unsigned short*>(&h);
}
__device__ __forceinline__ void async16(const void* g, void* l) {
  __builtin_amdgcn_global_load_lds((const __attribute__((address_space(1))) void*)g,
                                   (__attribute__((address_space(3))) void*)l, 16, 0, 0);
}
__device__ __forceinline__ float sigmoidf_(float z) {
  return 1.f / (1.f + __expf(-z));
}

// ---------------------------------------------------------------------------
// Kernel PRE (fused): blocks 0..2047   : gate logits + x->bf16
//                     blocks 2048..2815: weight transpose -> WbT bf16
//                     blocks 2816..2831: per-batch CSR (hist+scan+fill)
// ---------------------------------------------------------------------------
__global__ __launch_bounds__(256) void k_pre(
    const float* __restrict__ x, const int* __restrict__ deps,
    const int* __restrict__ parent, const int* __restrict__ mask,
    const float* __restrict__ wlg, const float* __restrict__ blg,
    const float* __restrict__ wcg, const float* __restrict__ bcg,
    const float* __restrict__ wpg, const float* __restrict__ bpg,
    const float* __restrict__ Epg, const float* __restrict__ Ecg,
    const float* __restrict__ Wl, const float* __restrict__ Wp,
    const float* __restrict__ Wc,
    unsigned short* __restrict__ xb, float4* __restrict__ gates,
    unsigned short* __restrict__ WbT,
    int* __restrict__ cnt, int* __restrict__ off, int* __restrict__ lists)
{
  __shared__ int hist[4096];
  __shared__ int tot[256];
  const int bx = blockIdx.x;
  const int tid = threadIdx.x;

  if (bx >= 2048) {
    if (bx < 2816) {                 // ---- weight transpose ----
      const int n = bx - 2048;
      const float* W = (n < 256) ? Wl : ((n < 512) ? Wp : Wc);
      WbT[(size_t)n * 256 + tid] = f2bf(W[(size_t)tid * 256 + (n & 255)]);
    } else {                         // ---- per-batch CSR ----
      const int b = bx - 2816;
      const int base = b << 12;
      #pragma unroll
      for (int j = 0; j < 16; ++j) hist[tid + j * 256] = 0;
      __syncthreads();
      for (int j = 0; j < 16; ++j) {
        const int i = base + j * 256 + tid;
        if (mask[i]) {
          const int p = parent[i];
          if (p > 0 && mask[base + p]) atomicAdd(&hist[p], 1);
        }
      }
      __syncthreads();
      int v[16], s = 0;
      #pragma unroll
      for (int j = 0; j < 16; ++j) { v[j] = hist[tid * 16 + j]; s += v[j]; }
      tot[tid] = s;
      __syncthreads();
      for (int o = 1; o < 256; o <<= 1) {
        int xx = (tid >= o) ? tot[tid - o] : 0;
        __syncthreads();
        tot[tid] += xx;
        __syncthreads();
      }
      int run = tot[tid] - s;        // exclusive prefix
      #pragma unroll
      for (int j = 0; j < 16; ++j) {
        const int k = tid * 16 + j;
        cnt[base + k] = v[j];
        off[base + k] = run;
        hist[k] = run;               // becomes the fill cursor
        run += v[j];
      }
      __syncthreads();
      for (int j = 0; j < 16; ++j) {
        const int i = base + j * 256 + tid;
        if (mask[i]) {
          const int p = parent[i];
          if (p > 0 && mask[base + p]) {
            const int pos = atomicAdd(&hist[p], 1);
            lists[base + pos] = i;
          }
        }
      }
    }
    return;
  }

  // ---- gates + bf16 convert ----
  const int lane = tid & 63;
  const int gw = (bx * 256 + tid) >> 6;
  const float4 wl4 = ((const float4*)wlg)[lane];
  const float4 wc4 = ((const float4*)wcg)[lane];
  const float4 wp4 = ((const float4*)wpg)[lane];
  const float bl0 = blg[0], bc0 = bcg[0], bp0 = bpg[0];
  for (int t = 0; t < 8; ++t) {
    const int i = gw * 8 + t;
    float4 xv = ((const float4*)x)[(size_t)i * 64 + lane];
    float sl = xv.x * wl4.x + xv.y * wl4.y + xv.z * wl4.z + xv.w * wl4.w;
    float sc = xv.x * wc4.x + xv.y * wc4.y + xv.z * wc4.z + xv.w * wc4.w;
    float sp = xv.x * wp4.x + xv.y * wp4.y + xv.z * wp4.z + xv.w * wp4.w;
    #pragma unroll
    for (int o = 32; o; o >>= 1) {
      sl += __shfl_xor(sl, o);
      sc += __shfl_xor(sc, o);
      sp += __shfl_xor(sp, o);
    }
    ushort4 u;
    u.x = f2bf(xv.x); u.y = f2bf(xv.y); u.z = f2bf(xv.z); u.w = f2bf(xv.w);
    ((ushort4*)xb)[(size_t)i * 64 + lane] = u;
    if (lane == 0) {
      int d = deps[i];
      float gl = sigmoidf_(sl + bl0);
      float gp = sigmoidf_(sp + bp0 + Epg[d]);
      float gc = sigmoidf_(sc + bc0 + Ecg[d]);
      gates[i] = make_float4(gl, gp, gc, 0.f);
    }
  }
}

// ---------------------------------------------------------------------------
// Kernel B: Y[65536][768] (bf16) = xb @ Wb.  128x128 tile, 4 waves, BK=64.
// 1-D grid, mb=bid/6 nb=bid%6 so the 6 blocks sharing an A-tile run
// back-to-back -> A fetched from HBM once, L3-hits for the rest.
// ---------------------------------------------------------------------------
__global__ __launch_bounds__(256) void k_gemm(
    const unsigned short* __restrict__ A,    // [M][256] bf16
    const unsigned short* __restrict__ Bt,   // [768][256] bf16 (N-major)
    unsigned short* __restrict__ Y)          // [M][768] bf16
{
  __shared__ unsigned short sh[2 * 128 * 64];
  unsigned short* lA = sh;
  unsigned short* lB = sh + 128 * 64;
  const int tid = threadIdx.x;
  const int wid = tid >> 6, lane = tid & 63;
  const int wm = wid >> 1, wn = wid & 1;
  const int bid = blockIdx.x;
  const int mb = bid / 6, nb = bid % 6;

  f32x4 acc[4][4] = {};
  const unsigned short* Ag = A + (size_t)mb * 128 * 256;
  const unsigned short* Bg = Bt + (size_t)nb * 128 * 256;
  const int srow = wid * 8 + (lane >> 3);   // staging row within 32-row sweep
  const int scol = (lane & 7) * 8;          // staging col (bf16)

  for (int kb = 0; kb < 256; kb += 64) {
    #pragma unroll
    for (int s = 0; s < 4; ++s) {
      char* dA = (char*)lA + s * 4096 + wid * 1024 + lane * 16;
      char* dB = (char*)lB + s * 4096 + wid * 1024 + lane * 16;
      async16(Ag + (size_t)(s * 32 + srow) * 256 + kb + scol, dA);
      async16(Bg + (size_t)(s * 32 + srow) * 256 + kb + scol, dB);
    }
    __syncthreads();
    #pragma unroll
    for (int kk = 0; kk < 64; kk += 32) {
      const int ko = kk + (lane >> 4) * 8;
      bf16x8 af[4], bv[4];
      #pragma unroll
      for (int m = 0; m < 4; ++m)
        af[m] = *(const bf16x8*)&lA[(wm * 64 + m * 16 + (lane & 15)) * 64 + ko];
      #pragma unroll
      for (int n = 0; n < 4; ++n)
        bv[n] = *(const bf16x8*)&lB[(wn * 64 + n * 16 + (lane & 15)) * 64 + ko];
      #pragma unroll
      for (int m = 0; m < 4; ++m)
        #pragma unroll
        for (int n = 0; n < 4; ++n)
          acc[m][n] = __builtin_amdgcn_mfma_f32_16x16x32_bf16(af[m], bv[n], acc[m][n], 0, 0, 0);
    }
    __syncthreads();
  }

  // Epilogue: fragments -> LDS (bf16, [128][128]) -> coalesced 16B stores.
  #pragma unroll
  for (int m = 0; m < 4; ++m)
    #pragma unroll
    for (int n = 0; n < 4; ++n)
      #pragma unroll
      for (int r = 0; r < 4; ++r)
        sh[(wm * 64 + m * 16 + (lane >> 4) * 4 + r) * 128 + wn * 64 + n * 16 + (lane & 15)]
            = f2bf(acc[m][n][r]);
  __syncthreads();
  #pragma unroll
  for (int s = 0; s < 8; ++s) {
    const int o = s * 4096 + tid * 16;          // byte offset in 32KB tile
    const int row = o >> 8;                     // 256 B per row (128 bf16)
    const int colu = (o & 255) >> 1;            // bf16 col
    *(i32x4*)&Y[(size_t)(mb * 128 + row) * 768 + nb * 128 + colu] =
        *(const i32x4*)((const char*)sh + o);
  }
}

// ---------------------------------------------------------------------------
// Kernel F: fused combine + child gather. One wave per output row; writes
// each row exactly once (zeros if masked). No atomics.
// ---------------------------------------------------------------------------
__global__ __launch_bounds__(256) void k_fused(
    const unsigned short* __restrict__ Y, const float4* __restrict__ gates,
    const int* __restrict__ parent, const int* __restrict__ deps,
    const int* __restrict__ mask, const int* __restrict__ cnt,
    const int* __restrict__ off, const int* __restrict__ lists,
    const float* __restrict__ b_loop, const float* __restrict__ b_parent,
    const float* __restrict__ b_child,
    const float* __restrict__ Epw, const float* __restrict__ Ecw,
    float* __restrict__ out)
{
  const int lane = threadIdx.x & 63;
  const int i = blockIdx.x * 4 + (threadIdx.x >> 6);   // output row (token)
  const int b = i >> 12;
  float4* orow = (float4*)(out + (size_t)i * 256) + lane;
  if (!mask[i]) { *orow = make_float4(0.f, 0.f, 0.f, 0.f); return; }

  const float4 g = gates[i];
  const int p = parent[i], d = deps[i];
  const float4 bl = ((const float4*)b_loop)[lane];
  const float4 bp = ((const float4*)b_parent)[lane];
  const ushort4 yl = ((const ushort4*)(Y + (size_t)i * 768))[lane];
  const ushort4 z  = ((const ushort4*)(Y + (size_t)((b << 12) + p) * 768 + 256))[lane];
  const float4 e   = ((const float4*)Epw)[d * 64 + lane];
  float4 o;
  o.x = g.x * (bf2f(yl.x) + bl.x) + g.y * (bf2f(z.x) + bp.x + e.x);
  o.y = g.x * (bf2f(yl.y) + bl.y) + g.y * (bf2f(z.y) + bp.y + e.y);
  o.z = g.x * (bf2f(yl.z) + bl.z) + g.y * (bf2f(z.z) + bp.z + e.z);
  o.w = g.x * (bf2f(yl.w) + bl.w) + g.y * (bf2f(z.w) + bp.w + e.w);

  const int n = cnt[i];
  if (n) {
    const int o0 = off[i];
    const float4 bc = ((const float4*)b_child)[lane];
    for (int k = 0; k < n; ++k) {
      const int c = lists[(b << 12) + o0 + k];
      const float gc = ((const float*)gates)[c * 4 + 2];
      const int dc = deps[c];
      const ushort4 yc = ((const ushort4*)(Y + (size_t)c * 768 + 512))[lane];
      const float4 ec = ((const float4*)Ecw)[dc * 64 + lane];
      o.x += gc * (bf2f(yc.x) + bc.x + ec.x);
      o.y += gc * (bf2f(yc.y) + bc.y + ec.y);
      o.z += gc * (bf2f(yc.z) + bc.z + ec.z);
      o.w += gc * (bf2f(yc.w) + bc.w + ec.w);
    }
  }
  *orow = o;
}

// ---------------------------------------------------------------------------
// Kernel R0: row-0 child reduction. 256 blocks (16 per batch), no fences:
// each block register+LDS-reduces 256 tokens' dest==0 contributions, then
// wave 0 adds its per-block partial into out row 0 via hardware f32 atomics
// (65K atomics over 4096 addresses, 16-way contention - negligible).
// Runs AFTER k_fused (adds on top of the loop+parent value it wrote).
// ---------------------------------------------------------------------------
__global__ __launch_bounds__(256) void k_row0(
    const unsigned short* __restrict__ Y, const float4* __restrict__ gates,
    const int* __restrict__ parent, const int* __restrict__ deps,
    const int* __restrict__ mask, const float* __restrict__ b_child,
    const float* __restrict__ Ecw, float* __restrict__ out)
{
  const int blk = blockIdx.x;          // 0..255
  const int b = blk >> 4;              // batch
  if (!mask[b << 12]) return;          // row 0 masked -> stays zero
  const int lane = threadIdx.x & 63;
  const int wid = threadIdx.x >> 6;
  const float4 bc = ((const float4*)b_child)[lane];
  float4 acc = make_float4(0.f, 0.f, 0.f, 0.f);
  const int tbase = (b << 12) + (blk & 15) * 256 + wid * 64;
  for (int t = 0; t < 64; ++t) {
    const int i = tbase + t;
    const int mi = mask[i];
    const int p = parent[i];
    if (mi && p != 0) continue;        // keep only dest==0 contributions
    const float gc = ((const float*)gates)[i * 4 + 2];
    const int d = deps[i];
    const ushort4 yc = ((const ushort4*)(Y + (size_t)i * 768 + 512))[lane];
    const float4 ec = ((const float4*)Ecw)[d * 64 + lane];
    acc.x += gc * (bf2f(yc.x) + bc.x + ec.x);
    acc.y += gc * (bf2f(yc.y) + bc.y + ec.y);
    acc.z += gc * (bf2f(yc.z) + bc.z + ec.z);
    acc.w += gc * (bf2f(yc.w) + bc.w + ec.w);
  }
  __shared__ float4 red[4][64];
  red[wid][lane] = acc;
  __syncthreads();
  if (wid == 0) {
    float4 a0 = red[0][lane], a1 = red[1][lane], a2 = red[2][lane], a3 = red[3][lane];
    a0.x += a1.x + a2.x + a3.x;
    a0.y += a1.y + a2.y + a3.y;
    a0.z += a1.z + a2.z + a3.z;
    a0.w += a1.w + a2.w + a3.w;
    float* dst = out + (size_t)(b << 12) * 256 + lane * 4;
    unsafeAtomicAdd(dst + 0, a0.x);
    unsafeAtomicAdd(dst + 1, a0.y);
    unsafeAtomicAdd(dst + 2, a0.z);
    unsafeAtomicAdd(dst + 3, a0.w);
  }
}

// ---------------------------------------------------------------------------
extern "C" void kernel_launch(void* const* d_in, const int* in_sizes, int n_in,
                              void* d_out, int out_size, void* d_ws, size_t ws_size,
                              hipStream_t stream) {
  const float* x        = (const float*)d_in[0];
  const int*   parent   = (const int*)d_in[1];
  const int*   deps     = (const int*)d_in[2];
  const int*   mask     = (const int*)d_in[3];
  const float* W_loop   = (const float*)d_in[4];
  const float* b_loop   = (const float*)d_in[5];
  const float* W_child  = (const float*)d_in[6];
  const float* b_child  = (const float*)d_in[7];
  const float* W_parent = (const float*)d_in[8];
  const float* b_parent = (const float*)d_in[9];
  const float* wlg      = (const float*)d_in[10];
  const float* blg      = (const float*)d_in[11];
  const float* wcg      = (const float*)d_in[12];
  const float* bcg      = (const float*)d_in[13];
  const float* wpg      = (const float*)d_in[14];
  const float* bpg      = (const float*)d_in[15];
  const float* Epw      = (const float*)d_in[16];
  const float* Ecw      = (const float*)d_in[17];
  const float* Epg      = (const float*)d_in[18];
  const float* Ecg      = (const float*)d_in[19];
  float* out = (float*)d_out;

  // Workspace layout (~136.2 MB)
  char* ws = (char*)d_ws;
  unsigned short* xb  = (unsigned short*)ws;                         // 32 MB
  unsigned short* WbT = (unsigned short*)(ws + 33554432);            // 384 KB
  float4* gates       = (float4*)(ws + 33947648);                    // 1 MB
  unsigned short* Yv  = (unsigned short*)(ws + 34996224);            // 96 MB
  int* cnt            = (int*)(ws + 135659520);                      // 256 KB
  int* off            = (int*)(ws + 135921664);                      // 256 KB
  int* lists          = (int*)(ws + 136183808);                      // 256 KB

  k_pre<<<2832, 256, 0, stream>>>(x, deps, parent, mask, wlg, blg, wcg, bcg,
                                  wpg, bpg, Epg, Ecg, W_loop, W_parent, W_child,
                                  xb, gates, WbT, cnt, off, lists);
  k_gemm<<<3072, 256, 0, stream>>>(xb, WbT, Yv);
  k_fused<<<16384, 256, 0, stream>>>(Yv, gates, parent, deps, mask, cnt, off,
                                     lists, b_loop, b_parent, b_child,
                                     Epw, Ecw, out);
  k_row0<<<256, 256, 0, stream>>>(Yv, gates, parent, deps, mask, b_child,
                                  Ecw, out);
}

// Round 8
// 267.840 us; speedup vs baseline: 1.2819x; 1.0410x over previous
//
#include <hip/hip_runtime.h>
#include <hip/hip_bf16.h>
#include <stdint.h>

// Problem constants
#define B_ 16
#define L_ 4096
#define D_ 256
#define M_ (B_*L_)   // 65536 tokens
#define N_ 768       // [loop | parent | child] concatenated output cols

typedef __attribute__((ext_vector_type(8))) short bf16x8;
typedef __attribute__((ext_vector_type(4))) float f32x4;
typedef __attribute__((ext_vector_type(4))) int i32x4;

__device__ __forceinline__ float bf2f(unsigned short u) {
  union { unsigned int i; float f; } v; v.i = ((unsigned int)u) << 16; return v.f;
}
__device__ __forceinline__ unsigned short f2bf(float f) {
  __hip_bfloat16 h = __float2bfloat16(f);
  return *reinterpret_cast<unsigned short*>(&h);
}
__device__ __forceinline__ void async16(const void* g, void* l) {
  __builtin_amdgcn_global_load_lds((const __attribute__((address_space(1))) void*)g,
                                   (__attribute__((address_space(3))) void*)l, 16, 0, 0);
}
__device__ __forceinline__ float sigmoidf_(float z) {
  return 1.f / (1.f + __expf(-z));
}

// ---------------------------------------------------------------------------
// Kernel PRE: blocks 0..2047  : gate logits + x->bf16 (unrolled, 24-way ILP
//                               across the shuffle-reduce chains)
//             blocks 2048..2239: weight transpose, 4 output cols per block
//                               (float4 source reads, coalesced bf16 stores)
// ---------------------------------------------------------------------------
__global__ __launch_bounds__(256) void k_pre(
    const float* __restrict__ x, const int* __restrict__ deps,
    const float* __restrict__ wlg, const float* __restrict__ blg,
    const float* __restrict__ wcg, const float* __restrict__ bcg,
    const float* __restrict__ wpg, const float* __restrict__ bpg,
    const float* __restrict__ Epg, const float* __restrict__ Ecg,
    const float* __restrict__ Wl, const float* __restrict__ Wp,
    const float* __restrict__ Wc,
    unsigned short* __restrict__ xb, float4* __restrict__ gates,
    unsigned short* __restrict__ WbT)
{
  const int bx = blockIdx.x;
  const int tid = threadIdx.x;

  if (bx >= 2048) {                  // ---- weight transpose ----
    const int n0 = (bx - 2048) * 4;  // 0..764
    const float* W = (n0 < 256) ? Wl : ((n0 < 512) ? Wp : Wc);
    const int c0 = n0 & 255;
    const float4 v = *(const float4*)&W[(size_t)tid * 256 + c0];
    WbT[(size_t)(n0 + 0) * 256 + tid] = f2bf(v.x);
    WbT[(size_t)(n0 + 1) * 256 + tid] = f2bf(v.y);
    WbT[(size_t)(n0 + 2) * 256 + tid] = f2bf(v.z);
    WbT[(size_t)(n0 + 3) * 256 + tid] = f2bf(v.w);
    return;
  }

  // ---- gates + bf16 convert ----
  const int lane = tid & 63;
  const int gw = (bx * 256 + tid) >> 6;
  const float4 wl4 = ((const float4*)wlg)[lane];
  const float4 wc4 = ((const float4*)wcg)[lane];
  const float4 wp4 = ((const float4*)wpg)[lane];
  const float bl0 = blg[0], bc0 = bcg[0], bp0 = bpg[0];
  float sl[8], sc[8], sp[8];
  #pragma unroll
  for (int t = 0; t < 8; ++t) {
    const int i = gw * 8 + t;
    const float4 xv = ((const float4*)x)[(size_t)i * 64 + lane];
    sl[t] = xv.x * wl4.x + xv.y * wl4.y + xv.z * wl4.z + xv.w * wl4.w;
    sc[t] = xv.x * wc4.x + xv.y * wc4.y + xv.z * wc4.z + xv.w * wc4.w;
    sp[t] = xv.x * wp4.x + xv.y * wp4.y + xv.z * wp4.z + xv.w * wp4.w;
    ushort4 u;
    u.x = f2bf(xv.x); u.y = f2bf(xv.y); u.z = f2bf(xv.z); u.w = f2bf(xv.w);
    ((ushort4*)xb)[(size_t)i * 64 + lane] = u;
  }
  #pragma unroll
  for (int o = 32; o; o >>= 1) {
    #pragma unroll
    for (int t = 0; t < 8; ++t) {
      sl[t] += __shfl_xor(sl[t], o);
      sc[t] += __shfl_xor(sc[t], o);
      sp[t] += __shfl_xor(sp[t], o);
    }
  }
  if (lane == 0) {
    #pragma unroll
    for (int t = 0; t < 8; ++t) {
      const int i = gw * 8 + t;
      const int d = deps[i];
      gates[i] = make_float4(sigmoidf_(sl[t] + bl0),
                             sigmoidf_(sp[t] + bp0 + Epg[d]),
                             sigmoidf_(sc[t] + bc0 + Ecg[d]), 0.f);
    }
  }
}

// ---------------------------------------------------------------------------
// Kernel B: blocks 0..15   : per-batch CSR (count+scan+fill, LDS carved from
//                            sh) + zero out row 0 of the batch. Runs first,
//                            fully hidden under the GEMM blocks.
//           blocks 16..3087: Y[65536][768] bf16 = xb @ Wb. 128x128 tile,
//                            4 waves, BK=64, 1-D walk (mb=bid/6, nb=bid%6)
//                            for A-tile L3 temporal locality.
// ---------------------------------------------------------------------------
__global__ __launch_bounds__(256) void k_gemm(
    const unsigned short* __restrict__ A,    // [M][256] bf16
    const unsigned short* __restrict__ Bt,   // [768][256] bf16 (N-major)
    unsigned short* __restrict__ Y,          // [M][768] bf16
    const int* __restrict__ parent, const int* __restrict__ mask,
    int* __restrict__ cnt, int* __restrict__ off, int* __restrict__ lists,
    float* __restrict__ out)
{
  __shared__ unsigned short sh[2 * 128 * 64];
  const int tid = threadIdx.x;

  if (blockIdx.x < 16) {             // ---- per-batch CSR + row0 zero ----
    int* hist = (int*)sh;            // 4096 ints (16 KB)
    int* tot = ((int*)sh) + 4096;    // 256 ints
    const int b = blockIdx.x;
    const int base = b << 12;
    out[(size_t)base * 256 + tid] = 0.f;   // zero row 0 (256 floats)
    #pragma unroll
    for (int j = 0; j < 16; ++j) hist[tid + j * 256] = 0;
    __syncthreads();
    for (int j = 0; j < 16; ++j) {
      const int i = base + j * 256 + tid;
      if (mask[i]) {
        const int p = parent[i];
        if (p > 0 && mask[base + p]) atomicAdd(&hist[p], 1);
      }
    }
    __syncthreads();
    int v[16], s = 0;
    #pragma unroll
    for (int j = 0; j < 16; ++j) { v[j] = hist[tid * 16 + j]; s += v[j]; }
    tot[tid] = s;
    __syncthreads();
    for (int o = 1; o < 256; o <<= 1) {
      int xx = (tid >= o) ? tot[tid - o] : 0;
      __syncthreads();
      tot[tid] += xx;
      __syncthreads();
    }
    int run = tot[tid] - s;          // exclusive prefix
    #pragma unroll
    for (int j = 0; j < 16; ++j) {
      const int k = tid * 16 + j;
      cnt[base + k] = v[j];
      off[base + k] = run;
      hist[k] = run;                 // becomes the fill cursor
      run += v[j];
    }
    __syncthreads();
    for (int j = 0; j < 16; ++j) {
      const int i = base + j * 256 + tid;
      if (mask[i]) {
        const int p = parent[i];
        if (p > 0 && mask[base + p]) {
          const int pos = atomicAdd(&hist[p], 1);
          lists[base + pos] = i;
        }
      }
    }
    return;
  }

  // ---- GEMM ----
  unsigned short* lA = sh;
  unsigned short* lB = sh + 128 * 64;
  const int wid = tid >> 6, lane = tid & 63;
  const int wm = wid >> 1, wn = wid & 1;
  const int bid = blockIdx.x - 16;
  const int mb = bid / 6, nb = bid % 6;

  f32x4 acc[4][4] = {};
  const unsigned short* Ag = A + (size_t)mb * 128 * 256;
  const unsigned short* Bg = Bt + (size_t)nb * 128 * 256;
  const int srow = wid * 8 + (lane >> 3);   // staging row within 32-row sweep
  const int scol = (lane & 7) * 8;          // staging col (bf16)

  for (int kb = 0; kb < 256; kb += 64) {
    #pragma unroll
    for (int s = 0; s < 4; ++s) {
      char* dA = (char*)lA + s * 4096 + wid * 1024 + lane * 16;
      char* dB = (char*)lB + s * 4096 + wid * 1024 + lane * 16;
      async16(Ag + (size_t)(s * 32 + srow) * 256 + kb + scol, dA);
      async16(Bg + (size_t)(s * 32 + srow) * 256 + kb + scol, dB);
    }
    __syncthreads();
    #pragma unroll
    for (int kk = 0; kk < 64; kk += 32) {
      const int ko = kk + (lane >> 4) * 8;
      bf16x8 af[4], bv[4];
      #pragma unroll
      for (int m = 0; m < 4; ++m)
        af[m] = *(const bf16x8*)&lA[(wm * 64 + m * 16 + (lane & 15)) * 64 + ko];
      #pragma unroll
      for (int n = 0; n < 4; ++n)
        bv[n] = *(const bf16x8*)&lB[(wn * 64 + n * 16 + (lane & 15)) * 64 + ko];
      #pragma unroll
      for (int m = 0; m < 4; ++m)
        #pragma unroll
        for (int n = 0; n < 4; ++n)
          acc[m][n] = __builtin_amdgcn_mfma_f32_16x16x32_bf16(af[m], bv[n], acc[m][n], 0, 0, 0);
    }
    __syncthreads();
  }

  // Epilogue: fragments -> LDS (bf16, [128][128]) -> coalesced 16B stores.
  #pragma unroll
  for (int m = 0; m < 4; ++m)
    #pragma unroll
    for (int n = 0; n < 4; ++n)
      #pragma unroll
      for (int r = 0; r < 4; ++r)
        sh[(wm * 64 + m * 16 + (lane >> 4) * 4 + r) * 128 + wn * 64 + n * 16 + (lane & 15)]
            = f2bf(acc[m][n][r]);
  __syncthreads();
  #pragma unroll
  for (int s = 0; s < 8; ++s) {
    const int o = s * 4096 + tid * 16;          // byte offset in 32KB tile
    const int row = o >> 8;                     // 256 B per row (128 bf16)
    const int colu = (o & 255) >> 1;            // bf16 col
    *(i32x4*)&Y[(size_t)(mb * 128 + row) * 768 + nb * 128 + colu] =
        *(const i32x4*)((const char*)sh + o);
  }
}

// ---------------------------------------------------------------------------
// Kernel F: blocks 0..16383   : fused combine + child gather, one wave per
//                               output row. Row 0 of each batch contributes
//                               via atomics (pre-zeroed in k_gemm dispatch).
//           blocks 16384..16639: row-0 child reduction (dest==0 funnel),
//                               per-block partial -> atomics. All row-0
//                               contributions commute; no ordering needed.
// ---------------------------------------------------------------------------
__global__ __launch_bounds__(256) void k_fused(
    const unsigned short* __restrict__ Y, const float4* __restrict__ gates,
    const int* __restrict__ parent, const int* __restrict__ deps,
    const int* __restrict__ mask, const int* __restrict__ cnt,
    const int* __restrict__ off, const int* __restrict__ lists,
    const float* __restrict__ b_loop, const float* __restrict__ b_parent,
    const float* __restrict__ b_child,
    const float* __restrict__ Epw, const float* __restrict__ Ecw,
    float* __restrict__ out)
{
  const int lane = threadIdx.x & 63;
  const int wid = threadIdx.x >> 6;

  if (blockIdx.x >= 16384) {         // ---- row-0 child reduction ----
    const int blk = blockIdx.x - 16384;  // 0..255
    const int b = blk >> 4;
    if (!mask[b << 12]) return;      // row 0 masked -> stays zero
    const float4 bc = ((const float4*)b_child)[lane];
    float4 acc = make_float4(0.f, 0.f, 0.f, 0.f);
    const int tbase = (b << 12) + (blk & 15) * 256 + wid * 64;
    for (int t = 0; t < 64; ++t) {
      const int i = tbase + t;
      const int mi = mask[i];
      const int p = parent[i];
      if (mi && p != 0) continue;    // keep only dest==0 contributions
      const float gc = ((const float*)gates)[i * 4 + 2];
      const int d = deps[i];
      const ushort4 yc = ((const ushort4*)(Y + (size_t)i * 768 + 512))[lane];
      const float4 ec = ((const float4*)Ecw)[d * 64 + lane];
      acc.x += gc * (bf2f(yc.x) + bc.x + ec.x);
      acc.y += gc * (bf2f(yc.y) + bc.y + ec.y);
      acc.z += gc * (bf2f(yc.z) + bc.z + ec.z);
      acc.w += gc * (bf2f(yc.w) + bc.w + ec.w);
    }
    __shared__ float4 red[4][64];
    red[wid][lane] = acc;
    __syncthreads();
    if (wid == 0) {
      float4 a0 = red[0][lane], a1 = red[1][lane], a2 = red[2][lane], a3 = red[3][lane];
      a0.x += a1.x + a2.x + a3.x;
      a0.y += a1.y + a2.y + a3.y;
      a0.z += a1.z + a2.z + a3.z;
      a0.w += a1.w + a2.w + a3.w;
      float* dst = out + (size_t)(b << 12) * 256 + lane * 4;
      unsafeAtomicAdd(dst + 0, a0.x);
      unsafeAtomicAdd(dst + 1, a0.y);
      unsafeAtomicAdd(dst + 2, a0.z);
      unsafeAtomicAdd(dst + 3, a0.w);
    }
    return;
  }

  // ---- per-row combine + child gather ----
  const int i = blockIdx.x * 4 + wid;   // output row (token)
  const int b = i >> 12;
  const bool isrow0 = (i & 4095) == 0;
  float4* orow = (float4*)(out + (size_t)i * 256) + lane;
  if (!mask[i]) {
    if (!isrow0) *orow = make_float4(0.f, 0.f, 0.f, 0.f);
    return;                          // row 0 already zeroed in k_gemm
  }

  const float4 g = gates[i];
  const int p = parent[i], d = deps[i];
  const float4 bl = ((const float4*)b_loop)[lane];
  const float4 bp = ((const float4*)b_parent)[lane];
  const ushort4 yl = ((const ushort4*)(Y + (size_t)i * 768))[lane];
  const ushort4 z  = ((const ushort4*)(Y + (size_t)((b << 12) + p) * 768 + 256))[lane];
  const float4 e   = ((const float4*)Epw)[d * 64 + lane];
  float4 o;
  o.x = g.x * (bf2f(yl.x) + bl.x) + g.y * (bf2f(z.x) + bp.x + e.x);
  o.y = g.x * (bf2f(yl.y) + bl.y) + g.y * (bf2f(z.y) + bp.y + e.y);
  o.z = g.x * (bf2f(yl.z) + bl.z) + g.y * (bf2f(z.z) + bp.z + e.z);
  o.w = g.x * (bf2f(yl.w) + bl.w) + g.y * (bf2f(z.w) + bp.w + e.w);

  const int n = cnt[i];
  if (n) {
    const int o0 = off[i];
    const float4 bc = ((const float4*)b_child)[lane];
    for (int k = 0; k < n; ++k) {
      const int c = lists[(b << 12) + o0 + k];
      const float gc = ((const float*)gates)[c * 4 + 2];
      const int dc = deps[c];
      const ushort4 yc = ((const ushort4*)(Y + (size_t)c * 768 + 512))[lane];
      const float4 ec = ((const float4*)Ecw)[dc * 64 + lane];
      o.x += gc * (bf2f(yc.x) + bc.x + ec.x);
      o.y += gc * (bf2f(yc.y) + bc.y + ec.y);
      o.z += gc * (bf2f(yc.z) + bc.z + ec.z);
      o.w += gc * (bf2f(yc.w) + bc.w + ec.w);
    }
  }
  if (isrow0) {                      // contribute atomically (pre-zeroed)
    float* dst = out + (size_t)i * 256 + lane * 4;
    unsafeAtomicAdd(dst + 0, o.x);
    unsafeAtomicAdd(dst + 1, o.y);
    unsafeAtomicAdd(dst + 2, o.z);
    unsafeAtomicAdd(dst + 3, o.w);
  } else {
    *orow = o;
  }
}

// ---------------------------------------------------------------------------
extern "C" void kernel_launch(void* const* d_in, const int* in_sizes, int n_in,
                              void* d_out, int out_size, void* d_ws, size_t ws_size,
                              hipStream_t stream) {
  const float* x        = (const float*)d_in[0];
  const int*   parent   = (const int*)d_in[1];
  const int*   deps     = (const int*)d_in[2];
  const int*   mask     = (const int*)d_in[3];
  const float* W_loop   = (const float*)d_in[4];
  const float* b_loop   = (const float*)d_in[5];
  const float* W_child  = (const float*)d_in[6];
  const float* b_child  = (const float*)d_in[7];
  const float* W_parent = (const float*)d_in[8];
  const float* b_parent = (const float*)d_in[9];
  const float* wlg      = (const float*)d_in[10];
  const float* blg      = (const float*)d_in[11];
  const float* wcg      = (const float*)d_in[12];
  const float* bcg      = (const float*)d_in[13];
  const float* wpg      = (const float*)d_in[14];
  const float* bpg      = (const float*)d_in[15];
  const float* Epw      = (const float*)d_in[16];
  const float* Ecw      = (const float*)d_in[17];
  const float* Epg      = (const float*)d_in[18];
  const float* Ecg      = (const float*)d_in[19];
  float* out = (float*)d_out;

  // Workspace layout (~136.2 MB)
  char* ws = (char*)d_ws;
  unsigned short* xb  = (unsigned short*)ws;                         // 32 MB
  unsigned short* WbT = (unsigned short*)(ws + 33554432);            // 384 KB
  float4* gates       = (float4*)(ws + 33947648);                    // 1 MB
  unsigned short* Yv  = (unsigned short*)(ws + 34996224);            // 96 MB
  int* cnt            = (int*)(ws + 135659520);                      // 256 KB
  int* off            = (int*)(ws + 135921664);                      // 256 KB
  int* lists          = (int*)(ws + 136183808);                      // 256 KB

  k_pre<<<2240, 256, 0, stream>>>(x, deps, wlg, blg, wcg, bcg, wpg, bpg,
                                  Epg, Ecg, W_loop, W_parent, W_child,
                                  xb, gates, WbT);
  k_gemm<<<3088, 256, 0, stream>>>(xb, WbT, Yv, parent, mask, cnt, off,
                                   lists, out);
  k_fused<<<16640, 256, 0, stream>>>(Yv, gates, parent, deps, mask, cnt, off,
                                     lists, b_loop, b_parent, b_child,
                                     Epw, Ecw, out);
}

// Round 9
// 263.763 us; speedup vs baseline: 1.3017x; 1.0155x over previous
//
#include <hip/hip_runtime.h>
#include <hip/hip_bf16.h>
#include <stdint.h>

// Problem constants
#define B_ 16
#define L_ 4096
#define D_ 256
#define M_ (B_*L_)   // 65536 tokens
#define N_ 768       // [loop | parent | child] concatenated output cols

typedef __attribute__((ext_vector_type(8))) short bf16x8;
typedef __attribute__((ext_vector_type(4))) float f32x4;
typedef __attribute__((ext_vector_type(4))) int i32x4;

__device__ __forceinline__ float bf2f(unsigned short u) {
  union { unsigned int i; float f; } v; v.i = ((unsigned int)u) << 16; return v.f;
}
__device__ __forceinline__ unsigned short f2bf(float f) {
  __hip_bfloat16 h = __float2bfloat16(f);
  return *reinterpret_cast<unsigned short*>(&h);
}
__device__ __forceinline__ void async16(const void* g, void* l) {
  __builtin_amdgcn_global_load_lds((const __attribute__((address_space(1))) void*)g,
                                   (__attribute__((address_space(3))) void*)l, 16, 0, 0);
}
__device__ __forceinline__ float sigmoidf_(float z) {
  return 1.f / (1.f + __expf(-z));
}

// ---------------------------------------------------------------------------
// Kernel PRE: blocks 0..15     : per-batch CSR (count+scan+fill) + zero row 0
//                                (launched FIRST -> no straggler tail)
//             blocks 16..2063  : gate logits + x->bf16 (24-way ILP reduce)
//             blocks 2064..2255: weight transpose, 4 cols/block
// ---------------------------------------------------------------------------
__global__ __launch_bounds__(256) void k_pre(
    const float* __restrict__ x, const int* __restrict__ deps,
    const int* __restrict__ parent, const int* __restrict__ mask,
    const float* __restrict__ wlg, const float* __restrict__ blg,
    const float* __restrict__ wcg, const float* __restrict__ bcg,
    const float* __restrict__ wpg, const float* __restrict__ bpg,
    const float* __restrict__ Epg, const float* __restrict__ Ecg,
    const float* __restrict__ Wl, const float* __restrict__ Wp,
    const float* __restrict__ Wc,
    unsigned short* __restrict__ xb, float4* __restrict__ gates,
    unsigned short* __restrict__ WbT,
    int* __restrict__ cnt, int* __restrict__ off, int* __restrict__ lists,
    float* __restrict__ out)
{
  __shared__ int hist[4096];
  __shared__ int tot[256];
  const int bx = blockIdx.x;
  const int tid = threadIdx.x;

  if (bx < 16) {                     // ---- per-batch CSR + row0 zero ----
    const int b = bx;
    const int base = b << 12;
    out[(size_t)base * 256 + tid] = 0.f;   // zero row 0 (256 floats)
    #pragma unroll
    for (int j = 0; j < 16; ++j) hist[tid + j * 256] = 0;
    __syncthreads();
    for (int j = 0; j < 16; ++j) {
      const int i = base + j * 256 + tid;
      if (mask[i]) {
        const int p = parent[i];
        if (p > 0 && mask[base + p]) atomicAdd(&hist[p], 1);
      }
    }
    __syncthreads();
    int v[16], s = 0;
    #pragma unroll
    for (int j = 0; j < 16; ++j) { v[j] = hist[tid * 16 + j]; s += v[j]; }
    tot[tid] = s;
    __syncthreads();
    for (int o = 1; o < 256; o <<= 1) {
      int xx = (tid >= o) ? tot[tid - o] : 0;
      __syncthreads();
      tot[tid] += xx;
      __syncthreads();
    }
    int run = tot[tid] - s;          // exclusive prefix
    #pragma unroll
    for (int j = 0; j < 16; ++j) {
      const int k = tid * 16 + j;
      cnt[base + k] = v[j];
      off[base + k] = run;
      hist[k] = run;                 // becomes the fill cursor
      run += v[j];
    }
    __syncthreads();
    for (int j = 0; j < 16; ++j) {
      const int i = base + j * 256 + tid;
      if (mask[i]) {
        const int p = parent[i];
        if (p > 0 && mask[base + p]) {
          const int pos = atomicAdd(&hist[p], 1);
          lists[base + pos] = i;
        }
      }
    }
    return;
  }

  if (bx >= 2064) {                  // ---- weight transpose ----
    const int n0 = (bx - 2064) * 4;  // 0..764
    const float* W = (n0 < 256) ? Wl : ((n0 < 512) ? Wp : Wc);
    const int c0 = n0 & 255;
    const float4 v = *(const float4*)&W[(size_t)tid * 256 + c0];
    WbT[(size_t)(n0 + 0) * 256 + tid] = f2bf(v.x);
    WbT[(size_t)(n0 + 1) * 256 + tid] = f2bf(v.y);
    WbT[(size_t)(n0 + 2) * 256 + tid] = f2bf(v.z);
    WbT[(size_t)(n0 + 3) * 256 + tid] = f2bf(v.w);
    return;
  }

  // ---- gates + bf16 convert ----
  const int lane = tid & 63;
  const int gw = ((bx - 16) * 256 + tid) >> 6;
  const float4 wl4 = ((const float4*)wlg)[lane];
  const float4 wc4 = ((const float4*)wcg)[lane];
  const float4 wp4 = ((const float4*)wpg)[lane];
  const float bl0 = blg[0], bc0 = bcg[0], bp0 = bpg[0];
  float sl[8], sc[8], sp[8];
  #pragma unroll
  for (int t = 0; t < 8; ++t) {
    const int i = gw * 8 + t;
    const float4 xv = ((const float4*)x)[(size_t)i * 64 + lane];
    sl[t] = xv.x * wl4.x + xv.y * wl4.y + xv.z * wl4.z + xv.w * wl4.w;
    sc[t] = xv.x * wc4.x + xv.y * wc4.y + xv.z * wc4.z + xv.w * wc4.w;
    sp[t] = xv.x * wp4.x + xv.y * wp4.y + xv.z * wp4.z + xv.w * wp4.w;
    ushort4 u;
    u.x = f2bf(xv.x); u.y = f2bf(xv.y); u.z = f2bf(xv.z); u.w = f2bf(xv.w);
    ((ushort4*)xb)[(size_t)i * 64 + lane] = u;
  }
  #pragma unroll
  for (int o = 32; o; o >>= 1) {
    #pragma unroll
    for (int t = 0; t < 8; ++t) {
      sl[t] += __shfl_xor(sl[t], o);
      sc[t] += __shfl_xor(sc[t], o);
      sp[t] += __shfl_xor(sp[t], o);
    }
  }
  if (lane == 0) {
    #pragma unroll
    for (int t = 0; t < 8; ++t) {
      const int i = gw * 8 + t;
      const int d = deps[i];
      gates[i] = make_float4(sigmoidf_(sl[t] + bl0),
                             sigmoidf_(sp[t] + bp0 + Epg[d]),
                             sigmoidf_(sc[t] + bc0 + Ecg[d]), 0.f);
    }
  }
}

// ---------------------------------------------------------------------------
// Kernel B: Y[65536][768] bf16 = xb @ Wb. 128x128 tile, 4 waves, BK=64.
// XCD-chunked walk: xcd=bid&7 (HW round-robin), local=bid>>3,
// mb=xcd*64+local/6, nb=local%6 -> the 6 blocks sharing an A-tile are
// CONSECUTIVE ON THE SAME XCD (same private L2) -> A fetched ~once.
// ---------------------------------------------------------------------------
__global__ __launch_bounds__(256) void k_gemm(
    const unsigned short* __restrict__ A,    // [M][256] bf16
    const unsigned short* __restrict__ Bt,   // [768][256] bf16 (N-major)
    unsigned short* __restrict__ Y)          // [M][768] bf16
{
  __shared__ unsigned short sh[2 * 128 * 64];
  unsigned short* lA = sh;
  unsigned short* lB = sh + 128 * 64;
  const int tid = threadIdx.x;
  const int wid = tid >> 6, lane = tid & 63;
  const int wm = wid >> 1, wn = wid & 1;
  const int bid = blockIdx.x;
  const int xcd = bid & 7;
  const int local = bid >> 3;              // 0..383
  const int mb = xcd * 64 + local / 6;     // 0..511
  const int nb = local % 6;                // 0..5

  f32x4 acc[4][4] = {};
  const unsigned short* Ag = A + (size_t)mb * 128 * 256;
  const unsigned short* Bg = Bt + (size_t)nb * 128 * 256;
  const int srow = wid * 8 + (lane >> 3);   // staging row within 32-row sweep
  const int scol = (lane & 7) * 8;          // staging col (bf16)

  for (int kb = 0; kb < 256; kb += 64) {
    #pragma unroll
    for (int s = 0; s < 4; ++s) {
      char* dA = (char*)lA + s * 4096 + wid * 1024 + lane * 16;
      char* dB = (char*)lB + s * 4096 + wid * 1024 + lane * 16;
      async16(Ag + (size_t)(s * 32 + srow) * 256 + kb + scol, dA);
      async16(Bg + (size_t)(s * 32 + srow) * 256 + kb + scol, dB);
    }
    __syncthreads();
    #pragma unroll
    for (int kk = 0; kk < 64; kk += 32) {
      const int ko = kk + (lane >> 4) * 8;
      bf16x8 af[4], bv[4];
      #pragma unroll
      for (int m = 0; m < 4; ++m)
        af[m] = *(const bf16x8*)&lA[(wm * 64 + m * 16 + (lane & 15)) * 64 + ko];
      #pragma unroll
      for (int n = 0; n < 4; ++n)
        bv[n] = *(const bf16x8*)&lB[(wn * 64 + n * 16 + (lane & 15)) * 64 + ko];
      #pragma unroll
      for (int m = 0; m < 4; ++m)
        #pragma unroll
        for (int n = 0; n < 4; ++n)
          acc[m][n] = __builtin_amdgcn_mfma_f32_16x16x32_bf16(af[m], bv[n], acc[m][n], 0, 0, 0);
    }
    __syncthreads();
  }

  // Epilogue: fragments -> LDS (bf16, [128][128]) -> coalesced 16B stores.
  #pragma unroll
  for (int m = 0; m < 4; ++m)
    #pragma unroll
    for (int n = 0; n < 4; ++n)
      #pragma unroll
      for (int r = 0; r < 4; ++r)
        sh[(wm * 64 + m * 16 + (lane >> 4) * 4 + r) * 128 + wn * 64 + n * 16 + (lane & 15)]
            = f2bf(acc[m][n][r]);
  __syncthreads();
  #pragma unroll
  for (int s = 0; s < 8; ++s) {
    const int o = s * 4096 + tid * 16;          // byte offset in 32KB tile
    const int row = o >> 8;                     // 256 B per row (128 bf16)
    const int colu = (o & 255) >> 1;            // bf16 col
    *(i32x4*)&Y[(size_t)(mb * 128 + row) * 768 + nb * 128 + colu] =
        *(const i32x4*)((const char*)sh + o);
  }
}

// ---------------------------------------------------------------------------
// Kernel F: blocks 0..16383   : fused combine + child gather, one wave per
//                               output row. Row 0 of each batch contributes
//                               via atomics (pre-zeroed in k_pre).
//           blocks 16384..16639: row-0 child reduction (dest==0 funnel),
//                               per-block partial -> atomics. All row-0
//                               contributions commute; no ordering needed.
// ---------------------------------------------------------------------------
__global__ __launch_bounds__(256) void k_fused(
    const unsigned short* __restrict__ Y, const float4* __restrict__ gates,
    const int* __restrict__ parent, const int* __restrict__ deps,
    const int* __restrict__ mask, const int* __restrict__ cnt,
    const int* __restrict__ off, const int* __restrict__ lists,
    const float* __restrict__ b_loop, const float* __restrict__ b_parent,
    const float* __restrict__ b_child,
    const float* __restrict__ Epw, const float* __restrict__ Ecw,
    float* __restrict__ out)
{
  const int lane = threadIdx.x & 63;
  const int wid = threadIdx.x >> 6;

  if (blockIdx.x >= 16384) {         // ---- row-0 child reduction ----
    const int blk = blockIdx.x - 16384;  // 0..255
    const int b = blk >> 4;
    if (!mask[b << 12]) return;      // row 0 masked -> stays zero
    const float4 bc = ((const float4*)b_child)[lane];
    float4 acc = make_float4(0.f, 0.f, 0.f, 0.f);
    const int tbase = (b << 12) + (blk & 15) * 256 + wid * 64;
    for (int t = 0; t < 64; ++t) {
      const int i = tbase + t;
      const int mi = mask[i];
      const int p = parent[i];
      if (mi && p != 0) continue;    // keep only dest==0 contributions
      const float gc = ((const float*)gates)[i * 4 + 2];
      const int d = deps[i];
      const ushort4 yc = ((const ushort4*)(Y + (size_t)i * 768 + 512))[lane];
      const float4 ec = ((const float4*)Ecw)[d * 64 + lane];
      acc.x += gc * (bf2f(yc.x) + bc.x + ec.x);
      acc.y += gc * (bf2f(yc.y) + bc.y + ec.y);
      acc.z += gc * (bf2f(yc.z) + bc.z + ec.z);
      acc.w += gc * (bf2f(yc.w) + bc.w + ec.w);
    }
    __shared__ float4 red[4][64];
    red[wid][lane] = acc;
    __syncthreads();
    if (wid == 0) {
      float4 a0 = red[0][lane], a1 = red[1][lane], a2 = red[2][lane], a3 = red[3][lane];
      a0.x += a1.x + a2.x + a3.x;
      a0.y += a1.y + a2.y + a3.y;
      a0.z += a1.z + a2.z + a3.z;
      a0.w += a1.w + a2.w + a3.w;
      float* dst = out + (size_t)(b << 12) * 256 + lane * 4;
      unsafeAtomicAdd(dst + 0, a0.x);
      unsafeAtomicAdd(dst + 1, a0.y);
      unsafeAtomicAdd(dst + 2, a0.z);
      unsafeAtomicAdd(dst + 3, a0.w);
    }
    return;
  }

  // ---- per-row combine + child gather ----
  const int i = blockIdx.x * 4 + wid;   // output row (token)
  const int b = i >> 12;
  const bool isrow0 = (i & 4095) == 0;
  float4* orow = (float4*)(out + (size_t)i * 256) + lane;
  if (!mask[i]) {
    if (!isrow0) *orow = make_float4(0.f, 0.f, 0.f, 0.f);
    return;                          // row 0 already zeroed in k_pre
  }

  const float4 g = gates[i];
  const int p = parent[i], d = deps[i];
  const float4 bl = ((const float4*)b_loop)[lane];
  const float4 bp = ((const float4*)b_parent)[lane];
  const ushort4 yl = ((const ushort4*)(Y + (size_t)i * 768))[lane];
  const ushort4 z  = ((const ushort4*)(Y + (size_t)((b << 12) + p) * 768 + 256))[lane];
  const float4 e   = ((const float4*)Epw)[d * 64 + lane];
  float4 o;
  o.x = g.x * (bf2f(yl.x) + bl.x) + g.y * (bf2f(z.x) + bp.x + e.x);
  o.y = g.x * (bf2f(yl.y) + bl.y) + g.y * (bf2f(z.y) + bp.y + e.y);
  o.z = g.x * (bf2f(yl.z) + bl.z) + g.y * (bf2f(z.z) + bp.z + e.z);
  o.w = g.x * (bf2f(yl.w) + bl.w) + g.y * (bf2f(z.w) + bp.w + e.w);

  const int n = cnt[i];
  if (n) {
    const int o0 = off[i];
    const float4 bc = ((const float4*)b_child)[lane];
    for (int k = 0; k < n; ++k) {
      const int c = lists[(b << 12) + o0 + k];
      const float gc = ((const float*)gates)[c * 4 + 2];
      const int dc = deps[c];
      const ushort4 yc = ((const ushort4*)(Y + (size_t)c * 768 + 512))[lane];
      const float4 ec = ((const float4*)Ecw)[dc * 64 + lane];
      o.x += gc * (bf2f(yc.x) + bc.x + ec.x);
      o.y += gc * (bf2f(yc.y) + bc.y + ec.y);
      o.z += gc * (bf2f(yc.z) + bc.z + ec.z);
      o.w += gc * (bf2f(yc.w) + bc.w + ec.w);
    }
  }
  if (isrow0) {                      // contribute atomically (pre-zeroed)
    float* dst = out + (size_t)i * 256 + lane * 4;
    unsafeAtomicAdd(dst + 0, o.x);
    unsafeAtomicAdd(dst + 1, o.y);
    unsafeAtomicAdd(dst + 2, o.z);
    unsafeAtomicAdd(dst + 3, o.w);
  } else {
    *orow = o;
  }
}

// ---------------------------------------------------------------------------
extern "C" void kernel_launch(void* const* d_in, const int* in_sizes, int n_in,
                              void* d_out, int out_size, void* d_ws, size_t ws_size,
                              hipStream_t stream) {
  const float* x        = (const float*)d_in[0];
  const int*   parent   = (const int*)d_in[1];
  const int*   deps     = (const int*)d_in[2];
  const int*   mask     = (const int*)d_in[3];
  const float* W_loop   = (const float*)d_in[4];
  const float* b_loop   = (const float*)d_in[5];
  const float* W_child  = (const float*)d_in[6];
  const float* b_child  = (const float*)d_in[7];
  const float* W_parent = (const float*)d_in[8];
  const float* b_parent = (const float*)d_in[9];
  const float* wlg      = (const float*)d_in[10];
  const float* blg      = (const float*)d_in[11];
  const float* wcg      = (const float*)d_in[12];
  const float* bcg      = (const float*)d_in[13];
  const float* wpg      = (const float*)d_in[14];
  const float* bpg      = (const float*)d_in[15];
  const float* Epw      = (const float*)d_in[16];
  const float* Ecw      = (const float*)d_in[17];
  const float* Epg      = (const float*)d_in[18];
  const float* Ecg      = (const float*)d_in[19];
  float* out = (float*)d_out;

  // Workspace layout (~136.2 MB)
  char* ws = (char*)d_ws;
  unsigned short* xb  = (unsigned short*)ws;                         // 32 MB
  unsigned short* WbT = (unsigned short*)(ws + 33554432);            // 384 KB
  float4* gates       = (float4*)(ws + 33947648);                    // 1 MB
  unsigned short* Yv  = (unsigned short*)(ws + 34996224);            // 96 MB
  int* cnt            = (int*)(ws + 135659520);                      // 256 KB
  int* off            = (int*)(ws + 135921664);                      // 256 KB
  int* lists          = (int*)(ws + 136183808);                      // 256 KB

  k_pre<<<2256, 256, 0, stream>>>(x, deps, parent, mask, wlg, blg, wcg, bcg,
                                  wpg, bpg, Epg, Ecg, W_loop, W_parent, W_child,
                                  xb, gates, WbT, cnt, off, lists, out);
  k_gemm<<<3072, 256, 0, stream>>>(xb, WbT, Yv);
  k_fused<<<16640, 256, 0, stream>>>(Yv, gates, parent, deps, mask, cnt, off,
                                     lists, b_loop, b_parent, b_child,
                                     Epw, Ecw, out);
}